// Round 10
// baseline (234.370 us; speedup 1.0000x reference)
//
#include <hip/hip_runtime.h>

// Inverse wavelet transform (Haar):
//   x: [4B, C, H, W] fp32, B=8, C=64, H=128, W=128 -> out: [B, C, 2H, 2W]
//
// Round-10 (= round-9 resubmitted after broker timeout): stream-count
// reduction via workgroup-cooperative LDS staging.
// r2/r4/r7/r8 pinned at ~80us / 2.5 TB/s regardless of store pattern, load
// width, ILP depth, wave count, NT stores. Reference points in the same
// environment: fillBuffer (1 stream/wave) 6.8 TB/s, float4 copy (2 streams)
// 6.3 TB/s, ours (6 streams/wave: 4 quarter-reads + 2 row-writes) 2.5 TB/s.
// This version: each wave loads ONE quarter (1 contiguous 1KB stream),
// stages in LDS, then writes ONE output row (1 contiguous 1KB NT stream).
//
// Block = 256 thr (4 waves) x PAIRS=4 iterations; per iter the block
// converts rows [i0,i0+1] of one channel (all 4 quarters) into output
// rows 2*i0..2*i0+3. Grid = 512 channels x 16 = 8192 blocks.

typedef float f2 __attribute__((ext_vector_type(2)));
typedef float f4 __attribute__((ext_vector_type(4)));

constexpr int H = 128, W = 128;
constexpr int HW = H * W;          // 16384 floats per (b,c) input plane
constexpr int OUT_ROW = 2 * W;     // 256 floats per output row
constexpr int OUT_PLANE = 4 * HW;  // 65536 floats per (b,c) output plane
constexpr int PAIRS = 4;           // input row-pairs per block

__global__ __launch_bounds__(256) void iwt_kernel(const float* __restrict__ x,
                                                  float* __restrict__ out,
                                                  int quarter)
{
    __shared__ f4 lds[4 * 64];  // [quarter][lane] = 4 KB: 2 input rows x 4 quarters

    const int t    = threadIdx.x;
    const int wq   = t >> 6;    // wave id: quarter (load phase) / out-row (store phase)
    const int lane = t & 63;

    const int cb  = blockIdx.x >> 4;   // channel-batch (b*C+c), 0..511
    const int ipg = blockIdx.x & 15;   // row-pair group

    // Load phase constants: wave wq streams quarter wq.
    const float* xq = x + wq * quarter + cb * HW + (lane << 2);

    // Store phase constants: wave wq writes output row (2*i0 + wq).
    const int ii_rel = wq >> 1;              // input row within the pair
    const int p      = wq & 1;               // output row parity
    const int u      = (ii_rel << 5) + (lane >> 1);  // f4 index inside a quarter region
    const int sub    = (lane & 1) << 1;              // float offset inside that f4
    const float* lbase = reinterpret_cast<const float*>(lds) + u * 4 + sub;
    float* obase = out + cb * OUT_PLANE + wq * OUT_ROW + (lane << 2);

#pragma unroll
    for (int it = 0; it < PAIRS; ++it) {
        const int ip = ipg * PAIRS + it;
        const int i0 = ip << 1;

        // 1 contiguous 1KB load per wave: rows [i0, i0+1] of quarter wq.
        f4 v = *reinterpret_cast<const f4*>(xq + i0 * W);

        __syncthreads();                 // previous iteration's LDS reads done
        lds[(wq << 6) + lane] = v;
        __syncthreads();                 // LDS filled

        // Each thread: float2 (cols 2c, 2c+1 of input row i0+ii_rel) per quarter.
        f2 v1 = *reinterpret_cast<const f2*>(lbase + 0 * 256);
        f2 v2 = *reinterpret_cast<const f2*>(lbase + 1 * 256);
        f2 v3 = *reinterpret_cast<const f2*>(lbase + 2 * 256);
        f2 v4 = *reinterpret_cast<const f2*>(lbase + 3 * 256);

        float a1 = v1[0] * 0.5f, a2 = v2[0] * 0.5f, a3 = v3[0] * 0.5f, a4 = v4[0] * 0.5f;
        float b1 = v1[1] * 0.5f, b2 = v2[1] * 0.5f, b3 = v3[1] * 0.5f, b4 = v4[1] * 0.5f;

        f4 o;
        if (p == 0) {                    // even output row: e00, e01
            o[0] = a1 - a2 - a3 + a4;
            o[1] = a1 + a2 - a3 - a4;
            o[2] = b1 - b2 - b3 + b4;
            o[3] = b1 + b2 - b3 - b4;
        } else {                         // odd output row: e10, e11
            o[0] = a1 - a2 + a3 - a4;
            o[1] = a1 + a2 + a3 + a4;
            o[2] = b1 - b2 + b3 - b4;
            o[3] = b1 + b2 + b3 + b4;
        }

        // 1 contiguous 1KB NT store per wave: output row 2*i0 + wq.
        __builtin_nontemporal_store(o, reinterpret_cast<f4*>(obase + (i0 << 1) * OUT_ROW));
    }
}

extern "C" void kernel_launch(void* const* d_in, const int* in_sizes, int n_in,
                              void* d_out, int out_size, void* d_ws, size_t ws_size,
                              hipStream_t stream) {
    const float* x = (const float*)d_in[0];
    float* out = (float*)d_out;

    const int quarter = in_sizes[0] / 4;            // 8,388,608
    const int n_cb    = quarter / HW;               // 512
    const int grid    = n_cb * (H / 2 / PAIRS);     // 512 * 16 = 8192
    const int block   = 256;

    iwt_kernel<<<grid, block, 0, stream>>>(x, out, quarter);
}